// Round 1
// 7340.406 us; speedup vs baseline: 2.5042x; 2.5042x over previous
//
#include <hip/hip_runtime.h>

typedef __bf16 bf16;
typedef __bf16 bf8v __attribute__((ext_vector_type(8)));
typedef float  f4v  __attribute__((ext_vector_type(4)));

#define L_   1024
#define D_   1024
#define H_   16
#define HD_  64
#define FF_  4096
#define NL_  8
#define NTOK 2048
#define LDSS 40

// Dual-pointer dtype-branching load: f==1 -> float32 at pf; f==0 -> bf16 at pb.
__device__ __forceinline__ float ldf2(const void* pb, const void* pf, size_t i, int f) {
  return f ? ((const float*)pf)[i] : (float)((const bf16*)pb)[i];
}

// ---------------- dtype detector ----------------
__global__ void dtype_detect(const unsigned short* __restrict__ raw, int* __restrict__ flag)
{
  int c = 0;
  for (int i = threadIdx.x; i < 1024; i += 64) c += (raw[i] >> 15) & 1;
#pragma unroll
  for (int off = 32; off > 0; off >>= 1) c += __shfl_down(c, off);
  if (threadIdx.x == 0) *flag = (c > 16) ? 1 : 0;
}

// ---------------- ws-too-small marker ----------------
__global__ void ws_marker(const int* __restrict__ flag, void* __restrict__ out)
{
  const int i = blockIdx.x * 256 + threadIdx.x;   // 0..2047
  if (*flag) ((float*)out)[i] = 100.0f;
  else       ((bf16*)out)[i]  = (bf16)100.0f;
}

// ---------------- embed ----------------
__global__ __launch_bounds__(256) void embed_kernel(
    const int* __restrict__ card_ids, const int* __restrict__ action_ids,
    const void* __restrict__ bet, const void* __restrict__ card_tab,
    const void* __restrict__ action_tab, const void* __restrict__ bet_W,
    const void* __restrict__ bet_b, const void* __restrict__ in_W,
    const void* __restrict__ in_b, const int* __restrict__ dflag,
    bf16* __restrict__ x)
{
  const int f = *dflag;
  const int t = blockIdx.x;          // 0..2047
  const int l = t & (L_ - 1);
  const int tid = threadIdx.x;
  __shared__ float tok[48];
  if (tid < 48) {
    float v;
    if (tid < 16)      v = ldf2(card_tab, card_tab, card_ids[t] * 16 + tid, f);
    else if (tid < 32) v = ldf2(action_tab, action_tab, action_ids[t] * 16 + (tid - 16), f);
    else               v = ldf2(bet, bet, t, f) * ldf2(bet_W, bet_W, tid - 32, f)
                           + ldf2(bet_b, bet_b, tid - 32, f);
    tok[tid] = v;
  }
  __syncthreads();
#pragma unroll
  for (int r = 0; r < 4; ++r) {
    const int n = tid + 256 * r;
    float acc = ldf2(in_b, in_b, n, f);
    for (int c = 0; c < 48; ++c) acc += tok[c] * ldf2(in_W, in_W, c * D_ + n, f);
    const float ang = (float)l * expf((float)(n & ~1) * (-9.210340371976184f / (float)D_));
    acc += (n & 1) ? cosf(ang) : sinf(ang);
    x[(size_t)t * D_ + n] = (bf16)acc;
  }
}

// ---------------- MFMA GEMM v2: 2-deep register prefetch + dbuf LDS + XCD col swizzle ----
// 128x128 tile, BK=32, 4 waves 2x2, each wave 4x4 mfma_f32_16x16x32_bf16.
// Pipeline per K-step t: issue global loads for t+2 (regs, raw dtype) ->
// compute tile t from LDS[t&1] -> cvt+ds_write tile t+1 into LDS[(t+1)&1] -> barrier.
// Reg staging (not global_load_lds) so the barrier only drains lgkmcnt, not vmcnt:
// prefetched loads stay in flight across the barrier.
// Grid is 1-D; col = bid % ncol so all blocks sharing a W column-panel land on the
// same XCD (ncol % 8 == 0 for every GEMM here) -> W panel is L2-resident per XCD.

#define GB_LOAD(T, X0, X1, WFA, WHA) do {                                   \
    const int kk_ = (((T) < nst) ? (T) : (nst - 1)) << 5;                   \
    X0 = *(const bf8v*)(Ap + kk_);                                          \
    X1 = *(const bf8v*)(Ap + kk_ + 8);                                      \
    const size_t wb_ = (size_t)(kk_ + bk) * N + n0 + bn;                    \
    _Pragma("unroll")                                                       \
    for (int j_ = 0; j_ < 16; ++j_) {                                       \
      if (F) WFA[j_] = Wf[wb_ + (size_t)j_ * N];                            \
      else   WHA[j_] = Wh[wb_ + (size_t)j_ * N];                            \
    }                                                                       \
  } while (0)

#define GB_WRITE(BUF, X0, X1, WFA, WHA) do {                                \
    *(bf8v*)(&As[BUF][ar * LDSS + ak])     = X0;                            \
    *(bf8v*)(&As[BUF][ar * LDSS + ak + 8]) = X1;                            \
    bf8v lo_, hi_;                                                          \
    _Pragma("unroll")                                                       \
    for (int j_ = 0; j_ < 8; ++j_) {                                        \
      lo_[j_] = F ? (bf16)WFA[j_]     : WHA[j_];                            \
      hi_[j_] = F ? (bf16)WFA[j_ + 8] : WHA[j_ + 8];                        \
    }                                                                       \
    *(bf8v*)(&Bs[BUF][bn * LDSS + bk])     = lo_;                           \
    *(bf8v*)(&Bs[BUF][bn * LDSS + bk + 8]) = hi_;                           \
  } while (0)

#define GB_COMPUTE(BUF) do {                                                \
    bf8v af_[4], bv_[4];                                                    \
    _Pragma("unroll")                                                       \
    for (int mt_ = 0; mt_ < 4; ++mt_)                                       \
      af_[mt_] = *(const bf8v*)(&As[BUF][(wm + mt_ * 16 + fr) * LDSS + quad * 8]); \
    _Pragma("unroll")                                                       \
    for (int nt_ = 0; nt_ < 4; ++nt_)                                       \
      bv_[nt_] = *(const bf8v*)(&Bs[BUF][(wn + nt_ * 16 + fr) * LDSS + quad * 8]); \
    _Pragma("unroll")                                                       \
    for (int mt_ = 0; mt_ < 4; ++mt_)                                       \
      _Pragma("unroll")                                                     \
      for (int nt_ = 0; nt_ < 4; ++nt_)                                     \
        acc[mt_][nt_] = __builtin_amdgcn_mfma_f32_16x16x32_bf16(af_[mt_], bv_[nt_], acc[mt_][nt_], 0, 0, 0); \
  } while (0)

template<int RELU, int F>
__device__ __forceinline__ void gemm_body(
    bf16 (* __restrict__ As)[128 * LDSS], bf16 (* __restrict__ Bs)[128 * LDSS],
    const bf16* __restrict__ A, const void* __restrict__ Wp,
    const void* __restrict__ Bp, bf16* __restrict__ C, int N, int K)
{
  const int tid  = threadIdx.x;
  const int ncol = N >> 7;
  const int bid  = blockIdx.x;
  const int n0   = (bid % ncol) * 128;
  const int m0   = (bid / ncol) * 128;
  const int lane = tid & 63;
  const int wave = tid >> 6;
  const int wm   = (wave >> 1) * 64;
  const int wn   = (wave & 1) * 64;
  const int fr   = lane & 15;   // fragment outer index
  const int quad = lane >> 4;   // k-quad

  const int ar = tid >> 1;            // A row 0..127
  const int ak = (tid & 1) * 16;      // A k-half
  const int bn = tid & 127;           // B col 0..127
  const int bk = (tid >> 7) * 16;     // B k-half

  const float* Wf = (const float*)Wp;
  const bf16*  Wh = (const bf16*)Wp;
  const bf16*  Ap = A + (size_t)(m0 + ar) * K + ak;
  const int    nst = K >> 5;          // K is a multiple of 64 -> nst even

  f4v acc[4][4];
#pragma unroll
  for (int i = 0; i < 4; ++i)
#pragma unroll
    for (int j = 0; j < 4; ++j) { f4v z = {0.f, 0.f, 0.f, 0.f}; acc[i][j] = z; }

  bf8v a00, a01, a10, a11;
  float wf0[16], wf1[16];
  bf16  wh0[16], wh1[16];

  GB_LOAD(0, a00, a01, wf0, wh0);
  GB_LOAD(1, a10, a11, wf1, wh1);
  GB_WRITE(0, a00, a01, wf0, wh0);
  __syncthreads();

  for (int t = 0; t < nst; t += 2) {
    // even step: compute buf0 (tile t), write tile t+1 -> buf1, prefetch tile t+2
    GB_LOAD(t + 2, a00, a01, wf0, wh0);
    GB_COMPUTE(0);
    GB_WRITE(1, a10, a11, wf1, wh1);
    __syncthreads();
    // odd step: compute buf1 (tile t+1), write tile t+2 -> buf0, prefetch tile t+3
    GB_LOAD(t + 3, a10, a11, wf1, wh1);
    GB_COMPUTE(1);
    GB_WRITE(0, a00, a01, wf0, wh0);
    __syncthreads();
  }

  // C/D layout: col=lane&15 (N, from B-frag), row=quad*4+reg (M, from A-frag)
#pragma unroll
  for (int nt = 0; nt < 4; ++nt) {
    const int col = n0 + wn + nt * 16 + fr;
    const float bv = F ? ((const float*)Bp)[col] : (float)((const bf16*)Bp)[col];
#pragma unroll
    for (int mt = 0; mt < 4; ++mt) {
#pragma unroll
      for (int r = 0; r < 4; ++r) {
        const int row = m0 + wm + mt * 16 + quad * 4 + r;
        float v = acc[mt][nt][r] + bv;
        if (RELU) v = fmaxf(v, 0.0f);
        C[(size_t)row * N + col] = (bf16)v;
      }
    }
  }
}

template<int RELU>
__global__ __launch_bounds__(256) void gemm_kernel(
    const bf16* __restrict__ A, const void* __restrict__ Wb, const void* __restrict__ Wf,
    const void* __restrict__ Bb, const void* __restrict__ Bf,
    const int* __restrict__ dflag, bf16* __restrict__ C, int M, int N, int K)
{
  __shared__ bf16 As[2][128 * LDSS];
  __shared__ bf16 Bs[2][128 * LDSS];
  (void)M;
  if (*dflag) gemm_body<RELU, 1>(As, Bs, A, Wf, Bf, C, N, K);
  else        gemm_body<RELU, 0>(As, Bs, A, Wb, Bb, C, N, K);
}

// ---------------- causal attention, one block per (b,h,q) ----------------
__global__ __launch_bounds__(256) void attn_kernel(
    const bf16* __restrict__ qkv, bf16* __restrict__ attno)
{
  const int q  = blockIdx.x;
  const int bh = blockIdx.y;
  const int b  = bh >> 4;
  const int h  = bh & 15;
  const int tid = threadIdx.x;

  __shared__ float sq[HD_];
  __shared__ float sc[L_];
  __shared__ float red[4];
  __shared__ float part[4][HD_];

  const size_t rs = 3 * D_;
  const bf16* qrow = qkv + (size_t)(b * L_ + q) * rs + h * HD_;
  if (tid < HD_) sq[tid] = (float)qrow[tid] * 0.125f;   // 1/sqrt(64)
  __syncthreads();

  const int nk = q + 1;
  const bf16* kbase = qkv + (size_t)(b * L_) * rs + D_ + h * HD_;
  for (int j = tid; j < nk; j += 256) {
    const bf8v* kp = (const bf8v*)(kbase + (size_t)j * rs);
    float dot = 0.f;
#pragma unroll
    for (int c = 0; c < 8; ++c) {
      bf8v kv = kp[c];
#pragma unroll
      for (int e = 0; e < 8; ++e) dot += sq[c * 8 + e] * (float)kv[e];
    }
    sc[j] = dot;
  }
  __syncthreads();

  float mx = -1e30f;
  for (int j = tid; j < nk; j += 256) mx = fmaxf(mx, sc[j]);
#pragma unroll
  for (int off = 32; off > 0; off >>= 1) mx = fmaxf(mx, __shfl_down(mx, off));
  if ((tid & 63) == 0) red[tid >> 6] = mx;
  __syncthreads();
  mx = fmaxf(fmaxf(red[0], red[1]), fmaxf(red[2], red[3]));
  __syncthreads();

  float s = 0.f;
  for (int j = tid; j < nk; j += 256) {
    float p = __expf(sc[j] - mx);
    sc[j] = p;
    s += p;
  }
#pragma unroll
  for (int off = 32; off > 0; off >>= 1) s += __shfl_down(s, off);
  if ((tid & 63) == 0) red[tid >> 6] = s;
  __syncthreads();
  const float inv = 1.f / (red[0] + red[1] + red[2] + red[3]);

  const int d = tid & 63;
  const int g = tid >> 6;
  const bf16* vp = qkv + (size_t)(b * L_) * rs + 2 * D_ + h * HD_ + d;
  float o = 0.f;
  for (int j = g; j < nk; j += 4) o += sc[j] * (float)vp[(size_t)j * rs];
  part[g][d] = o;
  __syncthreads();
  if (tid < HD_) {
    float r = (part[0][d] + part[1][d] + part[2][d] + part[3][d]) * inv;
    attno[(size_t)(b * L_ + q) * D_ + h * HD_ + d] = (bf16)r;
  }
}

// ---------------- fused residual-add + LayerNorm ----------------
__global__ __launch_bounds__(256) void add_ln_kernel(
    const bf16* __restrict__ xin, const bf16* __restrict__ yin,
    const void* __restrict__ gb, const void* __restrict__ gf,
    const void* __restrict__ bbb, const void* __restrict__ bbf,
    const int* __restrict__ dflag, bf16* __restrict__ xout)
{
  const int f = *dflag;
  const int t = blockIdx.x;
  const int tid = threadIdx.x;
  __shared__ float z[D_];
  __shared__ float red[4];
  const size_t base = (size_t)t * D_;
  float ls = 0.f;
#pragma unroll
  for (int r = 0; r < 4; ++r) {
    const int dd = tid + 256 * r;
    float v = (float)xin[base + dd] + (float)yin[base + dd];
    z[dd] = v;
    ls += v;
  }
#pragma unroll
  for (int off = 32; off > 0; off >>= 1) ls += __shfl_down(ls, off);
  if ((tid & 63) == 0) red[tid >> 6] = ls;
  __syncthreads();
  const float mu = (red[0] + red[1] + red[2] + red[3]) * (1.0f / D_);
  __syncthreads();
  float lv = 0.f;
#pragma unroll
  for (int r = 0; r < 4; ++r) {
    const float dv = z[tid + 256 * r] - mu;
    lv += dv * dv;
  }
#pragma unroll
  for (int off = 32; off > 0; off >>= 1) lv += __shfl_down(lv, off);
  if ((tid & 63) == 0) red[tid >> 6] = lv;
  __syncthreads();
  const float rstd = rsqrtf((red[0] + red[1] + red[2] + red[3]) * (1.0f / D_) + 1e-5f);
#pragma unroll
  for (int r = 0; r < 4; ++r) {
    const int dd = tid + 256 * r;
    const float v = (z[dd] - mu) * rstd * ldf2(gb, gf, dd, f) + ldf2(bbb, bbf, dd, f);
    xout[base + dd] = (bf16)v;
  }
}

// ---------------- final gather ----------------
__global__ void out_copy(const bf16* __restrict__ x, const int* __restrict__ dflag,
                         void* __restrict__ out)
{
  const int f = *dflag;
  const int i = blockIdx.x * 256 + threadIdx.x;   // 0..2047
  const int b = i >> 10;
  const int dd = i & 1023;
  const float v = (float)x[(size_t)(b * L_ + (L_ - 1)) * D_ + dd];
  if (f) ((float*)out)[i] = v;
  else   ((bf16*)out)[i]  = (bf16)v;
}

static inline const void* adv2(const void* p, size_t eoff) { return (const char*)p + eoff * 2; }
static inline const void* adv4(const void* p, size_t eoff) { return (const char*)p + eoff * 4; }

extern "C" void kernel_launch(void* const* d_in, const int* in_sizes, int n_in,
                              void* d_out, int out_size, void* d_ws, size_t ws_size,
                              hipStream_t stream)
{
  const int* card_ids   = (const int*)d_in[0];
  const int* action_ids = (const int*)d_in[1];

  char* ws = (char*)d_ws;
  int* dflag = (int*)ws;
  const size_t MB = 1u << 20;
  bf16* qkvbuf = (bf16*)(ws + 4096);
  bf16* attno  = (bf16*)(ws + 4096 + 12 * MB);
  bf16* hffn   = (bf16*)(ws + 4096);
  bf16* proj   = (bf16*)(ws + 4096 + 16 * MB);
  bf16* xbuf   = (bf16*)(ws + 4096 + 20 * MB);
  bf16* x2buf  = (bf16*)(ws + 4096 + 24 * MB);

  dtype_detect<<<1, 64, 0, stream>>>((const unsigned short*)d_in[2], dflag);

  if (ws_size < 4096 + 28 * MB) {            // constant across calls -> capture-safe
    ws_marker<<<NTOK / 256, 256, 0, stream>>>(dflag, d_out);
    return;
  }

  embed_kernel<<<NTOK, 256, 0, stream>>>(card_ids, action_ids, d_in[2], d_in[3],
                                         d_in[4], d_in[5], d_in[6], d_in[7], d_in[8],
                                         dflag, xbuf);

  for (int i = 0; i < NL_; ++i) {
    const size_t qW = (size_t)i * D_ * 3 * D_, qB = (size_t)i * 3 * D_;
    const size_t oW = (size_t)i * D_ * D_,     oB = (size_t)i * D_;
    const size_t w1 = (size_t)i * D_ * FF_,    b1 = (size_t)i * FF_;
    const size_t w2 = (size_t)i * FF_ * D_,    b2 = (size_t)i * D_;
    const size_t ln = (size_t)i * D_;

    // 1-D grids: ncol*nrow blocks; col = bid % ncol (ncol % 8 == 0 -> XCD panel locality)
    gemm_kernel<0><<<(3 * D_ / 128) * (NTOK / 128), 256, 0, stream>>>(
        xbuf, adv2(d_in[9], qW), adv4(d_in[9], qW), adv2(d_in[10], qB), adv4(d_in[10], qB),
        dflag, qkvbuf, NTOK, 3 * D_, D_);
    attn_kernel<<<dim3(L_, 2 * H_), 256, 0, stream>>>(qkvbuf, attno);
    gemm_kernel<0><<<(D_ / 128) * (NTOK / 128), 256, 0, stream>>>(
        attno, adv2(d_in[11], oW), adv4(d_in[11], oW), adv2(d_in[12], oB), adv4(d_in[12], oB),
        dflag, proj, NTOK, D_, D_);
    add_ln_kernel<<<NTOK, 256, 0, stream>>>(
        xbuf, proj, adv2(d_in[13], ln), adv4(d_in[13], ln), adv2(d_in[14], ln), adv4(d_in[14], ln),
        dflag, x2buf);
    gemm_kernel<1><<<(FF_ / 128) * (NTOK / 128), 256, 0, stream>>>(
        x2buf, adv2(d_in[15], w1), adv4(d_in[15], w1), adv2(d_in[16], b1), adv4(d_in[16], b1),
        dflag, hffn, NTOK, FF_, D_);
    gemm_kernel<0><<<(D_ / 128) * (NTOK / 128), 256, 0, stream>>>(
        hffn, adv2(d_in[17], w2), adv4(d_in[17], w2), adv2(d_in[18], b2), adv4(d_in[18], b2),
        dflag, proj, NTOK, D_, FF_);
    add_ln_kernel<<<NTOK, 256, 0, stream>>>(
        x2buf, proj, adv2(d_in[19], ln), adv4(d_in[19], ln), adv2(d_in[20], ln), adv4(d_in[20], ln),
        dflag, xbuf);
  }

  out_copy<<<NTOK / 256, 256, 0, stream>>>(xbuf, dflag, d_out);
}

// Round 2
// 2205.346 us; speedup vs baseline: 8.3352x; 3.3285x over previous
//
#include <hip/hip_runtime.h>

typedef __bf16 bf16;
typedef __bf16 bf8v __attribute__((ext_vector_type(8)));
typedef float  f4v  __attribute__((ext_vector_type(4)));

#define L_   1024
#define D_   1024
#define H_   16
#define HD_  64
#define FF_  4096
#define NL_  8
#define NTOK 2048
#define LDSS 40

// Dual-pointer dtype-branching load: f==1 -> float32 at pf; f==0 -> bf16 at pb.
__device__ __forceinline__ float ldf2(const void* pb, const void* pf, size_t i, int f) {
  return f ? ((const float*)pf)[i] : (float)((const bf16*)pb)[i];
}

// ---------------- dtype detector ----------------
__global__ void dtype_detect(const unsigned short* __restrict__ raw, int* __restrict__ flag)
{
  int c = 0;
  for (int i = threadIdx.x; i < 1024; i += 64) c += (raw[i] >> 15) & 1;
#pragma unroll
  for (int off = 32; off > 0; off >>= 1) c += __shfl_down(c, off);
  if (threadIdx.x == 0) *flag = (c > 16) ? 1 : 0;
}

// ---------------- ws-too-small marker ----------------
__global__ void ws_marker(const int* __restrict__ flag, void* __restrict__ out)
{
  const int i = blockIdx.x * 256 + threadIdx.x;   // 0..2047
  if (*flag) ((float*)out)[i] = 100.0f;
  else       ((bf16*)out)[i]  = (bf16)100.0f;
}

// ---------------- embed ----------------
__global__ __launch_bounds__(256) void embed_kernel(
    const int* __restrict__ card_ids, const int* __restrict__ action_ids,
    const void* __restrict__ bet, const void* __restrict__ card_tab,
    const void* __restrict__ action_tab, const void* __restrict__ bet_W,
    const void* __restrict__ bet_b, const void* __restrict__ in_W,
    const void* __restrict__ in_b, const int* __restrict__ dflag,
    bf16* __restrict__ x)
{
  const int f = *dflag;
  const int t = blockIdx.x;          // 0..2047
  const int l = t & (L_ - 1);
  const int tid = threadIdx.x;
  __shared__ float tok[48];
  if (tid < 48) {
    float v;
    if (tid < 16)      v = ldf2(card_tab, card_tab, card_ids[t] * 16 + tid, f);
    else if (tid < 32) v = ldf2(action_tab, action_tab, action_ids[t] * 16 + (tid - 16), f);
    else               v = ldf2(bet, bet, t, f) * ldf2(bet_W, bet_W, tid - 32, f)
                           + ldf2(bet_b, bet_b, tid - 32, f);
    tok[tid] = v;
  }
  __syncthreads();
#pragma unroll
  for (int r = 0; r < 4; ++r) {
    const int n = tid + 256 * r;
    float acc = ldf2(in_b, in_b, n, f);
    for (int c = 0; c < 48; ++c) acc += tok[c] * ldf2(in_W, in_W, c * D_ + n, f);
    const float ang = (float)l * expf((float)(n & ~1) * (-9.210340371976184f / (float)D_));
    acc += (n & 1) ? cosf(ang) : sinf(ang);
    x[(size_t)t * D_ + n] = (bf16)acc;
  }
}

// ---------------- MFMA GEMM v2: 2-deep register prefetch + dbuf LDS + XCD col swizzle ----
#define GB_LOAD(T, X0, X1, WFA, WHA) do {                                   \
    const int kk_ = (((T) < nst) ? (T) : (nst - 1)) << 5;                   \
    X0 = *(const bf8v*)(Ap + kk_);                                          \
    X1 = *(const bf8v*)(Ap + kk_ + 8);                                      \
    const size_t wb_ = (size_t)(kk_ + bk) * N + n0 + bn;                    \
    _Pragma("unroll")                                                       \
    for (int j_ = 0; j_ < 16; ++j_) {                                       \
      if (F) WFA[j_] = Wf[wb_ + (size_t)j_ * N];                            \
      else   WHA[j_] = Wh[wb_ + (size_t)j_ * N];                            \
    }                                                                       \
  } while (0)

#define GB_WRITE(BUF, X0, X1, WFA, WHA) do {                                \
    *(bf8v*)(&As[BUF][ar * LDSS + ak])     = X0;                            \
    *(bf8v*)(&As[BUF][ar * LDSS + ak + 8]) = X1;                            \
    bf8v lo_, hi_;                                                          \
    _Pragma("unroll")                                                       \
    for (int j_ = 0; j_ < 8; ++j_) {                                        \
      lo_[j_] = F ? (bf16)WFA[j_]     : WHA[j_];                            \
      hi_[j_] = F ? (bf16)WFA[j_ + 8] : WHA[j_ + 8];                        \
    }                                                                       \
    *(bf8v*)(&Bs[BUF][bn * LDSS + bk])     = lo_;                           \
    *(bf8v*)(&Bs[BUF][bn * LDSS + bk + 8]) = hi_;                           \
  } while (0)

#define GB_COMPUTE(BUF) do {                                                \
    bf8v af_[4], bv_[4];                                                    \
    _Pragma("unroll")                                                       \
    for (int mt_ = 0; mt_ < 4; ++mt_)                                       \
      af_[mt_] = *(const bf8v*)(&As[BUF][(wm + mt_ * 16 + fr) * LDSS + quad * 8]); \
    _Pragma("unroll")                                                       \
    for (int nt_ = 0; nt_ < 4; ++nt_)                                       \
      bv_[nt_] = *(const bf8v*)(&Bs[BUF][(wn + nt_ * 16 + fr) * LDSS + quad * 8]); \
    _Pragma("unroll")                                                       \
    for (int mt_ = 0; mt_ < 4; ++mt_)                                       \
      _Pragma("unroll")                                                     \
      for (int nt_ = 0; nt_ < 4; ++nt_)                                     \
        acc[mt_][nt_] = __builtin_amdgcn_mfma_f32_16x16x32_bf16(af_[mt_], bv_[nt_], acc[mt_][nt_], 0, 0, 0); \
  } while (0)

template<int RELU, int F>
__device__ __forceinline__ void gemm_body(
    bf16 (* __restrict__ As)[128 * LDSS], bf16 (* __restrict__ Bs)[128 * LDSS],
    const bf16* __restrict__ A, const void* __restrict__ Wp,
    const void* __restrict__ Bp, bf16* __restrict__ C, int N, int K)
{
  const int tid  = threadIdx.x;
  const int ncol = N >> 7;
  const int bid  = blockIdx.x;
  const int n0   = (bid % ncol) * 128;
  const int m0   = (bid / ncol) * 128;
  const int lane = tid & 63;
  const int wave = tid >> 6;
  const int wm   = (wave >> 1) * 64;
  const int wn   = (wave & 1) * 64;
  const int fr   = lane & 15;
  const int quad = lane >> 4;

  const int ar = tid >> 1;            // A row 0..127
  const int ak = (tid & 1) * 16;      // A k-half
  const int bn = tid & 127;           // B col 0..127
  const int bk = (tid >> 7) * 16;     // B k-half

  const float* Wf = (const float*)Wp;
  const bf16*  Wh = (const bf16*)Wp;
  const bf16*  Ap = A + (size_t)(m0 + ar) * K + ak;
  const int    nst = K >> 5;          // even (K multiple of 64)

  f4v acc[4][4];
#pragma unroll
  for (int i = 0; i < 4; ++i)
#pragma unroll
    for (int j = 0; j < 4; ++j) { f4v z = {0.f, 0.f, 0.f, 0.f}; acc[i][j] = z; }

  bf8v a00, a01, a10, a11;
  float wf0[16], wf1[16];
  bf16  wh0[16], wh1[16];

  GB_LOAD(0, a00, a01, wf0, wh0);
  GB_LOAD(1, a10, a11, wf1, wh1);
  GB_WRITE(0, a00, a01, wf0, wh0);
  __syncthreads();

  for (int t = 0; t < nst; t += 2) {
    GB_LOAD(t + 2, a00, a01, wf0, wh0);
    GB_COMPUTE(0);
    GB_WRITE(1, a10, a11, wf1, wh1);
    __syncthreads();
    GB_LOAD(t + 3, a10, a11, wf1, wh1);
    GB_COMPUTE(1);
    GB_WRITE(0, a00, a01, wf0, wh0);
    __syncthreads();
  }

  // C/D layout: col=lane&15 (N), row=quad*4+reg (M)
#pragma unroll
  for (int nt = 0; nt < 4; ++nt) {
    const int col = n0 + wn + nt * 16 + fr;
    const float bv = F ? ((const float*)Bp)[col] : (float)((const bf16*)Bp)[col];
#pragma unroll
    for (int mt = 0; mt < 4; ++mt) {
#pragma unroll
      for (int r = 0; r < 4; ++r) {
        const int row = m0 + wm + mt * 16 + quad * 4 + r;
        float v = acc[mt][nt][r] + bv;
        if (RELU) v = fmaxf(v, 0.0f);
        C[(size_t)row * N + col] = (bf16)v;
      }
    }
  }
}

template<int RELU>
__global__ __launch_bounds__(256) void gemm_kernel(
    const bf16* __restrict__ A, const void* __restrict__ Wb, const void* __restrict__ Wf,
    const void* __restrict__ Bb, const void* __restrict__ Bf,
    const int* __restrict__ dflag, bf16* __restrict__ C, int M, int N, int K)
{
  __shared__ bf16 As[2][128 * LDSS];
  __shared__ bf16 Bs[2][128 * LDSS];
  (void)M;
  if (*dflag) gemm_body<RELU, 1>(As, Bs, A, Wf, Bf, C, N, K);
  else        gemm_body<RELU, 0>(As, Bs, A, Wb, Bb, C, N, K);
}

// ---------------- MFMA flash attention ----------------
// Block = (b, h, 64-query tile); 4 waves x 16 q-rows.
// Q: registers (A-frags, direct global 16B loads).
// K: consumed directly from global as B-frags (L2-resident per XCD).
// V: staged transposed Vt[d][k] (stride 72 -> aligned ds_read_b128 B-frags),
//    double-buffered, prefetch-issue-early/write-late (one barrier per tile).
// Online softmax per 16-lane group (shfl_xor 1/2/4/8); P -> per-wave LDS
// scratch for the C-layout -> A-frag transpose.
#define LDT 72
__global__ __launch_bounds__(256) void attn_kernel(
    const bf16* __restrict__ qkv, bf16* __restrict__ attno)
{
  const int bid = blockIdx.x;          // 512 blocks: bid = idx*32 + bh
  const int idx = bid >> 5;            // 0..15
  const int bh  = bid & 31;            // bid%8 == bh%8 -> per-head XCD locality
  const int qt  = (idx < 8) ? idx : 23 - idx;   // pair heavy+light q-tiles per CU
  const int b   = bh >> 4;
  const int h   = bh & 15;
  const int tid = threadIdx.x;
  const int lane = tid & 63;
  const int wq   = tid >> 6;           // wave -> q sub-tile
  const int fr   = lane & 15;
  const int quad = lane >> 4;

  __shared__ bf16 Vt[2][64 * LDT];     // [buf][d][k] transposed V tile
  __shared__ bf16 Ps[4][16 * LDT];     // per-wave P tile [q][k]

  const size_t rs = 3 * D_;
  const size_t tokbase = (size_t)b * L_ * rs;
  const int q0 = qt * 64;

  // Q A-fragments: row = q0 + wq*16 + fr, k elems = (quad*8..)+{0,32}
  const bf16* qp = qkv + tokbase + (size_t)(q0 + wq * 16 + fr) * rs + h * HD_ + quad * 8;
  const bf8v qa0 = *(const bf8v*)qp;
  const bf8v qa1 = *(const bf8v*)(qp + 32);

  // V staging: lane-major rows (conflict-free transposed LDS writes)
  const int vr = lane;                 // k-row within tile
  const int vd = wq * 16;              // d-col group
  const bf16* vg = qkv + tokbase + 2 * D_ + h * HD_ + vd;

  const int ntile = qt + 1;
  const int qr_base = q0 + wq * 16 + quad * 4;   // C-layout q-row base

  f4v oacc[4];
#pragma unroll
  for (int nt = 0; nt < 4; ++nt) { f4v z = {0.f, 0.f, 0.f, 0.f}; oacc[nt] = z; }
  float mrow[4] = {-1e30f, -1e30f, -1e30f, -1e30f};
  float lrow[4] = {0.f, 0.f, 0.f, 0.f};

  // prologue: stage V tile 0
  {
    const bf8v v0 = *(const bf8v*)(vg + (size_t)vr * rs);
    const bf8v v1 = *(const bf8v*)(vg + (size_t)vr * rs + 8);
#pragma unroll
    for (int e = 0; e < 8; ++e) {
      Vt[0][(vd + e) * LDT + vr]     = v0[e];
      Vt[0][(vd + 8 + e) * LDT + vr] = v1[e];
    }
  }
  __syncthreads();

  for (int t = 0; t < ntile; ++t) {
    const int k0  = t * 64;
    const int cur = t & 1;
    const int more = (t + 1 < ntile);

    // prefetch next V tile into regs (latency hides under S/softmax/PV)
    bf8v vn0, vn1;
    if (more) {
      vn0 = *(const bf8v*)(vg + (size_t)(k0 + 64 + vr) * rs);
      vn1 = *(const bf8v*)(vg + (size_t)(k0 + 64 + vr) * rs + 8);
    }

    // S = Q @ K^T : B-frags straight from global (row = k0+nt*16+fr)
    f4v s[4];
#pragma unroll
    for (int nt = 0; nt < 4; ++nt) { f4v z = {0.f, 0.f, 0.f, 0.f}; s[nt] = z; }
#pragma unroll
    for (int nt = 0; nt < 4; ++nt) {
      const bf16* kp = qkv + tokbase + (size_t)(k0 + nt * 16 + fr) * rs + D_ + h * HD_ + quad * 8;
      const bf8v kb0 = *(const bf8v*)kp;
      const bf8v kb1 = *(const bf8v*)(kp + 32);
      s[nt] = __builtin_amdgcn_mfma_f32_16x16x32_bf16(qa0, kb0, s[nt], 0, 0, 0);
      s[nt] = __builtin_amdgcn_mfma_f32_16x16x32_bf16(qa1, kb1, s[nt], 0, 0, 0);
    }

    // scale + causal mask + online softmax (per q-row = quad*4+r)
#pragma unroll
    for (int r = 0; r < 4; ++r) {
      const int qr = qr_base + r;
      float mt = -1e30f;
#pragma unroll
      for (int nt = 0; nt < 4; ++nt) {
        float v = s[nt][r] * 0.125f;
        v = (k0 + nt * 16 + fr > qr) ? -1e30f : v;
        s[nt][r] = v;
        mt = fmaxf(mt, v);
      }
      mt = fmaxf(mt, __shfl_xor(mt, 1));
      mt = fmaxf(mt, __shfl_xor(mt, 2));
      mt = fmaxf(mt, __shfl_xor(mt, 4));
      mt = fmaxf(mt, __shfl_xor(mt, 8));
      const float mn = fmaxf(mrow[r], mt);
      const float sf = __expf(mrow[r] - mn);
      mrow[r] = mn;
      float ps = 0.f;
#pragma unroll
      for (int nt = 0; nt < 4; ++nt) {
        const float p = __expf(s[nt][r] - mn);
        ps += p;
        Ps[wq][(quad * 4 + r) * LDT + nt * 16 + fr] = (bf16)p;
      }
      ps += __shfl_xor(ps, 1);
      ps += __shfl_xor(ps, 2);
      ps += __shfl_xor(ps, 4);
      ps += __shfl_xor(ps, 8);
      lrow[r] = lrow[r] * sf + ps;
#pragma unroll
      for (int nt = 0; nt < 4; ++nt) oacc[nt][r] *= sf;
    }

    // P A-frags (wave-local LDS transpose): row = fr, k = kq*32 + quad*8
    const bf8v pa0 = *(const bf8v*)(&Ps[wq][fr * LDT + quad * 8]);
    const bf8v pa1 = *(const bf8v*)(&Ps[wq][fr * LDT + 32 + quad * 8]);

    // O += P @ V : B-frags from transposed Vt (contiguous b128, aligned)
#pragma unroll
    for (int nt = 0; nt < 4; ++nt) {
      const bf8v vb0 = *(const bf8v*)(&Vt[cur][(nt * 16 + fr) * LDT + quad * 8]);
      const bf8v vb1 = *(const bf8v*)(&Vt[cur][(nt * 16 + fr) * LDT + 32 + quad * 8]);
      oacc[nt] = __builtin_amdgcn_mfma_f32_16x16x32_bf16(pa0, vb0, oacc[nt], 0, 0, 0);
      oacc[nt] = __builtin_amdgcn_mfma_f32_16x16x32_bf16(pa1, vb1, oacc[nt], 0, 0, 0);
    }

    // write-late: next V tile -> other buffer; one barrier per tile
    if (more) {
#pragma unroll
      for (int e = 0; e < 8; ++e) {
        Vt[cur ^ 1][(vd + e) * LDT + vr]     = vn0[e];
        Vt[cur ^ 1][(vd + 8 + e) * LDT + vr] = vn1[e];
      }
    }
    __syncthreads();
  }

  // epilogue: O /= l, store
#pragma unroll
  for (int r = 0; r < 4; ++r) {
    const float inv = 1.f / lrow[r];
    bf16* op = attno + (size_t)(b * L_ + qr_base + r) * D_ + h * HD_;
#pragma unroll
    for (int nt = 0; nt < 4; ++nt)
      op[nt * 16 + fr] = (bf16)(oacc[nt][r] * inv);
  }
}

// ---------------- fused residual-add + LayerNorm ----------------
__global__ __launch_bounds__(256) void add_ln_kernel(
    const bf16* __restrict__ xin, const bf16* __restrict__ yin,
    const void* __restrict__ gb, const void* __restrict__ gf,
    const void* __restrict__ bbb, const void* __restrict__ bbf,
    const int* __restrict__ dflag, bf16* __restrict__ xout)
{
  const int f = *dflag;
  const int t = blockIdx.x;
  const int tid = threadIdx.x;
  __shared__ float z[D_];
  __shared__ float red[4];
  const size_t base = (size_t)t * D_;
  float ls = 0.f;
#pragma unroll
  for (int r = 0; r < 4; ++r) {
    const int dd = tid + 256 * r;
    float v = (float)xin[base + dd] + (float)yin[base + dd];
    z[dd] = v;
    ls += v;
  }
#pragma unroll
  for (int off = 32; off > 0; off >>= 1) ls += __shfl_down(ls, off);
  if ((tid & 63) == 0) red[tid >> 6] = ls;
  __syncthreads();
  const float mu = (red[0] + red[1] + red[2] + red[3]) * (1.0f / D_);
  __syncthreads();
  float lv = 0.f;
#pragma unroll
  for (int r = 0; r < 4; ++r) {
    const float dv = z[tid + 256 * r] - mu;
    lv += dv * dv;
  }
#pragma unroll
  for (int off = 32; off > 0; off >>= 1) lv += __shfl_down(lv, off);
  if ((tid & 63) == 0) red[tid >> 6] = lv;
  __syncthreads();
  const float rstd = rsqrtf((red[0] + red[1] + red[2] + red[3]) * (1.0f / D_) + 1e-5f);
#pragma unroll
  for (int r = 0; r < 4; ++r) {
    const int dd = tid + 256 * r;
    const float v = (z[dd] - mu) * rstd * ldf2(gb, gf, dd, f) + ldf2(bbb, bbf, dd, f);
    xout[base + dd] = (bf16)v;
  }
}

// ---------------- final gather ----------------
__global__ void out_copy(const bf16* __restrict__ x, const int* __restrict__ dflag,
                         void* __restrict__ out)
{
  const int f = *dflag;
  const int i = blockIdx.x * 256 + threadIdx.x;   // 0..2047
  const int b = i >> 10;
  const int dd = i & 1023;
  const float v = (float)x[(size_t)(b * L_ + (L_ - 1)) * D_ + dd];
  if (f) ((float*)out)[i] = v;
  else   ((bf16*)out)[i]  = (bf16)v;
}

static inline const void* adv2(const void* p, size_t eoff) { return (const char*)p + eoff * 2; }
static inline const void* adv4(const void* p, size_t eoff) { return (const char*)p + eoff * 4; }

extern "C" void kernel_launch(void* const* d_in, const int* in_sizes, int n_in,
                              void* d_out, int out_size, void* d_ws, size_t ws_size,
                              hipStream_t stream)
{
  const int* card_ids   = (const int*)d_in[0];
  const int* action_ids = (const int*)d_in[1];

  char* ws = (char*)d_ws;
  int* dflag = (int*)ws;
  const size_t MB = 1u << 20;
  bf16* qkvbuf = (bf16*)(ws + 4096);
  bf16* attno  = (bf16*)(ws + 4096 + 12 * MB);
  bf16* hffn   = (bf16*)(ws + 4096);
  bf16* proj   = (bf16*)(ws + 4096 + 16 * MB);
  bf16* xbuf   = (bf16*)(ws + 4096 + 20 * MB);
  bf16* x2buf  = (bf16*)(ws + 4096 + 24 * MB);

  dtype_detect<<<1, 64, 0, stream>>>((const unsigned short*)d_in[2], dflag);

  if (ws_size < 4096 + 28 * MB) {            // constant across calls -> capture-safe
    ws_marker<<<NTOK / 256, 256, 0, stream>>>(dflag, d_out);
    return;
  }

  embed_kernel<<<NTOK, 256, 0, stream>>>(card_ids, action_ids, d_in[2], d_in[3],
                                         d_in[4], d_in[5], d_in[6], d_in[7], d_in[8],
                                         dflag, xbuf);

  for (int i = 0; i < NL_; ++i) {
    const size_t qW = (size_t)i * D_ * 3 * D_, qB = (size_t)i * 3 * D_;
    const size_t oW = (size_t)i * D_ * D_,     oB = (size_t)i * D_;
    const size_t w1 = (size_t)i * D_ * FF_,    b1 = (size_t)i * FF_;
    const size_t w2 = (size_t)i * FF_ * D_,    b2 = (size_t)i * D_;
    const size_t ln = (size_t)i * D_;

    gemm_kernel<0><<<(3 * D_ / 128) * (NTOK / 128), 256, 0, stream>>>(
        xbuf, adv2(d_in[9], qW), adv4(d_in[9], qW), adv2(d_in[10], qB), adv4(d_in[10], qB),
        dflag, qkvbuf, NTOK, 3 * D_, D_);
    attn_kernel<<<512, 256, 0, stream>>>(qkvbuf, attno);
    gemm_kernel<0><<<(D_ / 128) * (NTOK / 128), 256, 0, stream>>>(
        attno, adv2(d_in[11], oW), adv4(d_in[11], oW), adv2(d_in[12], oB), adv4(d_in[12], oB),
        dflag, proj, NTOK, D_, D_);
    add_ln_kernel<<<NTOK, 256, 0, stream>>>(
        xbuf, proj, adv2(d_in[13], ln), adv4(d_in[13], ln), adv2(d_in[14], ln), adv4(d_in[14], ln),
        dflag, x2buf);
    gemm_kernel<1><<<(FF_ / 128) * (NTOK / 128), 256, 0, stream>>>(
        x2buf, adv2(d_in[15], w1), adv4(d_in[15], w1), adv2(d_in[16], b1), adv4(d_in[16], b1),
        dflag, hffn, NTOK, FF_, D_);
    gemm_kernel<0><<<(D_ / 128) * (NTOK / 128), 256, 0, stream>>>(
        hffn, adv2(d_in[17], w2), adv4(d_in[17], w2), adv2(d_in[18], b2), adv4(d_in[18], b2),
        dflag, proj, NTOK, D_, FF_);
    add_ln_kernel<<<NTOK, 256, 0, stream>>>(
        x2buf, proj, adv2(d_in[19], ln), adv4(d_in[19], ln), adv2(d_in[20], ln), adv4(d_in[20], ln),
        dflag, xbuf);
  }

  out_copy<<<NTOK / 256, 256, 0, stream>>>(xbuf, dflag, d_out);
}